// Round 3
// baseline (493.062 us; speedup 1.0000x reference)
//
#include <hip/hip_runtime.h>
#include <hip/hip_bf16.h>

// AttentionPooling: N=262144 nodes, DIM=256, H=4, HD=64, B=4096 segments (batch sorted).
// All float tensors fp32 (reference dtypes); output fp32. batch int32 or int64 (runtime guard).
// Algebra: attn logits and v are both linear in x, so fold query into key_w once
// (qw[4][256], qb[4]) and defer the value projection to after segment pooling:
//   pooled[b,o] = inv * (value_w[o,:] . Sraw[b,h,:]) + (sum_e*inv) * value_b[o]
//   Sraw[b,h,:] = sum_{n in b} exp(attn[n,h]) * x[n,:]
// => x (256 MB fp32) is read exactly ONCE. One block per segment; batch sorted so
// segments are contiguous; binary search for bounds; no atomics.

constexpr int DIM = 256;
constexpr int NH  = 4;
constexpr int HD  = 64;
constexpr float SCL  = 0.125f;   // HD^-0.5
constexpr float EPSV = 1e-8f;

// ---- prep: qw[h][j] = sum_d query[h,d]*key_w[h*64+d, j]; qb[h] = q . key_b ----
__global__ void prep_qw(const float* __restrict__ query,
                        const float* __restrict__ key_w,
                        const float* __restrict__ key_b,
                        float* __restrict__ ws){
  int t = blockIdx.x * 256 + threadIdx.x;   // 0..1023
  int h = t >> 8, j = t & 255;
  float acc = 0.f;
  for (int d = 0; d < HD; ++d)
    acc += query[h*HD+d] * key_w[(size_t)(h*HD+d)*DIM + j];
  ws[t] = acc;
  if (j == 0){
    float bb = 0.f;
    for (int d = 0; d < HD; ++d)
      bb += query[h*HD+d] * key_b[h*HD+d];
    ws[1024 + h] = bb;
  }
}

// ---- main: one block (256 thr = 4 waves) per segment ----
__global__ __launch_bounds__(256)
void attn_pool(const float* __restrict__ x,
               const int* __restrict__ batch32,
               const float* __restrict__ value_w,
               const float* __restrict__ value_b,
               const float* __restrict__ ws,
               float* __restrict__ out,
               int N){
  __shared__ __align__(16) float S_all[4][NH][DIM];   // 16 KB: per-wave partial S
  __shared__ __align__(16) float Sfin[NH][DIM];       // 4 KB
  __shared__ float sums_all[4][NH];
  __shared__ float invs[NH], wsums[NH];
  __shared__ int seg_bounds[2];

  const int b   = blockIdx.x;
  const int tid = threadIdx.x;

  if (tid < 2){
    // batch may be int64 (2 words/elem, high word 0) or int32; detect:
    // if int32, batch32[N-1] is the sorted max (~B-1, nonzero); if int64 it's a high word = 0.
    const bool is64 = (batch32[N-1] == 0);
    int target = b + tid;
    int lo = 0, hi = N;
    while (lo < hi){
      int mid = (lo + hi) >> 1;
      int v = is64 ? batch32[2*mid] : batch32[mid];
      if (v < target) lo = mid + 1; else hi = mid;
    }
    seg_bounds[tid] = lo;
  }
  __syncthreads();
  const int seg_start = seg_bounds[0], seg_end = seg_bounds[1];

  const int wave = tid >> 6, lane = tid & 63;
  const int half = lane >> 5, sl = lane & 31;   // half-wave owns one 256-col row (8 fp32/lane)

  // lane-resident qw fragment: columns sl*8 .. sl*8+7, all 4 heads (fp32, 32 VGPRs)
  float qwr[NH][8];
  #pragma unroll
  for (int h = 0; h < NH; ++h){
    const float4* q4 = (const float4*)(ws + h*DIM + sl*8);
    float4 a = q4[0], c = q4[1];
    qwr[h][0]=a.x; qwr[h][1]=a.y; qwr[h][2]=a.z; qwr[h][3]=a.w;
    qwr[h][4]=c.x; qwr[h][5]=c.y; qwr[h][6]=c.z; qwr[h][7]=c.w;
  }
  float qb[NH];
  #pragma unroll
  for (int h = 0; h < NH; ++h) qb[h] = ws[1024 + h];

  float Sacc[NH][8];
  #pragma unroll
  for (int h = 0; h < NH; ++h)
    #pragma unroll
    for (int c = 0; c < 8; ++c) Sacc[h][c] = 0.f;
  float se[NH] = {0.f, 0.f, 0.f, 0.f};

  const float4* xr4 = (const float4*)x;   // one row = 64 float4 (256 fp32)

  // each (wave,half) processes nodes seg_start + 8k + wave*2 + half (uniform per half-wave)
  for (int n = seg_start + wave*2 + half; n < seg_end; n += 8){
    float4 ra = xr4[(size_t)n * 64 + sl*2];
    float4 rb = xr4[(size_t)n * 64 + sl*2 + 1];
    float xv[8];
    xv[0]=ra.x; xv[1]=ra.y; xv[2]=ra.z; xv[3]=ra.w;
    xv[4]=rb.x; xv[5]=rb.y; xv[6]=rb.z; xv[7]=rb.w;

    float p[NH];
    #pragma unroll
    for (int h = 0; h < NH; ++h){
      float a = 0.f;
      #pragma unroll
      for (int c = 0; c < 8; ++c) a += qwr[h][c] * xv[c];
      p[h] = a;
    }
    // half-wave butterfly (masks <32 stay inside the active half)
    #pragma unroll
    for (int m = 1; m < 32; m <<= 1){
      #pragma unroll
      for (int h = 0; h < NH; ++h) p[h] += __shfl_xor(p[h], m, 64);
    }
    float e[NH];
    #pragma unroll
    for (int h = 0; h < NH; ++h){
      e[h] = __expf((p[h] + qb[h]) * SCL);
      se[h] += e[h];
    }
    #pragma unroll
    for (int h = 0; h < NH; ++h)
      #pragma unroll
      for (int c = 0; c < 8; ++c) Sacc[h][c] += e[h] * xv[c];
  }

  // combine the two halves of each wave (same columns, different nodes)
  #pragma unroll
  for (int h = 0; h < NH; ++h){
    se[h] += __shfl_xor(se[h], 32, 64);
    #pragma unroll
    for (int c = 0; c < 8; ++c) Sacc[h][c] += __shfl_xor(Sacc[h][c], 32, 64);
  }
  if (half == 0){
    #pragma unroll
    for (int h = 0; h < NH; ++h){
      float4 lo = make_float4(Sacc[h][0], Sacc[h][1], Sacc[h][2], Sacc[h][3]);
      float4 hi = make_float4(Sacc[h][4], Sacc[h][5], Sacc[h][6], Sacc[h][7]);
      float4* dst = (float4*)&S_all[wave][h][sl*8];
      dst[0] = lo; dst[1] = hi;
    }
    if (sl == 0){
      #pragma unroll
      for (int h = 0; h < NH; ++h) sums_all[wave][h] = se[h];
    }
  }
  __syncthreads();

  // reduce 4 wave-copies; thread t owns column t
  #pragma unroll
  for (int h = 0; h < NH; ++h)
    Sfin[h][tid] = S_all[0][h][tid] + S_all[1][h][tid] + S_all[2][h][tid] + S_all[3][h][tid];
  if (tid < NH){
    float tot = sums_all[0][tid] + sums_all[1][tid] + sums_all[2][tid] + sums_all[3][tid];
    float inv = 1.f / (tot + EPSV);
    invs[tid]  = inv;
    wsums[tid] = tot * inv;   // sum of normalized weights
  }
  __syncthreads();

  // epilogue: out[b, t] = inv * (value_w[t,:] . Sfin[h,:]) + wsum * value_b[t]
  const int h = tid >> 6;
  const float inv = invs[h], wsm = wsums[h];
  const float4* vrow = (const float4*)(value_w + (size_t)tid * DIM);  // fp32 row, L2-resident
  const float4* sp   = (const float4*)&Sfin[h][0];                    // broadcast reads
  float acc = 0.f;
  #pragma unroll
  for (int q = 0; q < 64; ++q){
    float4 r = vrow[q];
    float4 s = sp[q];
    acc += r.x*s.x + r.y*s.y + r.z*s.z + r.w*s.w;
  }
  out[(size_t)b * DIM + tid] = acc * inv + wsm * value_b[tid];
}

extern "C" void kernel_launch(void* const* d_in, const int* in_sizes, int n_in,
                              void* d_out, int out_size, void* d_ws, size_t ws_size,
                              hipStream_t stream){
  const float* x       = (const float*)d_in[0];
  const int*   batch   = (const int*)d_in[1];
  const float* query   = (const float*)d_in[2];
  const float* key_w   = (const float*)d_in[3];
  const float* key_b   = (const float*)d_in[4];
  const float* value_w = (const float*)d_in[5];
  const float* value_b = (const float*)d_in[6];
  float* ws  = (float*)d_ws;            // [0..1023] qw, [1024..1027] qb
  float* out = (float*)d_out;

  const int N = in_sizes[1];        // 262144
  const int B = out_size / DIM;     // 4096

  prep_qw<<<4, 256, 0, stream>>>(query, key_w, key_b, ws);
  attn_pool<<<B, 256, 0, stream>>>(x, batch, value_w, value_b, ws, out, N);
}

// Round 4
// 471.998 us; speedup vs baseline: 1.0446x; 1.0446x over previous
//
#include <hip/hip_runtime.h>
#include <hip/hip_bf16.h>

// AttentionPooling: N=262144 nodes, DIM=256, H=4, HD=64, B=4096 segments (batch sorted).
// All float tensors fp32; output fp32. batch int32 or int64 (runtime guard).
// Algebra: attn logits and v are both linear in x => fold query into key_w once
// (qw[4][256], qb[4]) and defer the value projection to after segment pooling:
//   pooled[b,o] = inv * (value_w[o,:] . Sraw[b,h,:]) + (sum_e*inv) * value_b[o]
//   Sraw[b,h,:] = sum_{n in b} exp(attn[n,h]) * x[n,:]
// => x (256 MB fp32) is read exactly ONCE. One block per segment (batch sorted).
//
// R4 changes vs R3 (228 us, VALUBusy 16%, VGPR_Count 64 -> spilled qwr/Sacc):
//  - __launch_bounds__(256, 4): 128-VGPR budget; live set ~105 regs fits, no spills.
//  - segment bounds precomputed by a boundary-detect kernel (kills the 18-step
//    dependent-load binary search prologue per block).

constexpr int DIM = 256;
constexpr int NH  = 4;
constexpr int HD  = 64;
constexpr float SCL  = 0.125f;   // HD^-0.5
constexpr float EPSV = 1e-8f;

// ---- prep: qw[h][j] = sum_d query[h,d]*key_w[h*64+d, j]; qb[h] = q . key_b ----
__global__ void prep_qw(const float* __restrict__ query,
                        const float* __restrict__ key_w,
                        const float* __restrict__ key_b,
                        float* __restrict__ ws){
  int t = blockIdx.x * 256 + threadIdx.x;   // 0..1023
  int h = t >> 8, j = t & 255;
  float acc = 0.f;
  for (int d = 0; d < HD; ++d)
    acc += query[h*HD+d] * key_w[(size_t)(h*HD+d)*DIM + j];
  ws[t] = acc;
  if (j == 0){
    float bb = 0.f;
    for (int d = 0; d < HD; ++d)
      bb += query[h*HD+d] * key_b[h*HD+d];
    ws[1024 + h] = bb;
  }
}

// ---- segment offsets: offs[b] = first index i with batch[i] >= b; offs[B] = N ----
__global__ void seg_offsets(const int* __restrict__ batch32,
                            int* __restrict__ offs, int N, int B){
  int i = blockIdx.x * 256 + threadIdx.x;
  if (i >= N) return;
  // int64 layout => int32 view of element N-1's high word (index N-1 is odd-position
  // high word when elements are 2 words); sorted max ~B-1 is nonzero for int32.
  const bool is64 = (batch32[N-1] == 0);
  int v  = is64 ? batch32[2*i] : batch32[i];
  int vp = (i == 0) ? -1 : (is64 ? batch32[2*(i-1)] : batch32[i-1]);
  for (int b = vp + 1; b <= v; ++b) offs[b] = i;
  if (i == N-1)
    for (int b = v + 1; b <= B; ++b) offs[b] = N;
}

// ---- main: one block (256 thr = 4 waves) per segment ----
__global__ __launch_bounds__(256, 4)
void attn_pool(const float* __restrict__ x,
               const int* __restrict__ offs,
               const float* __restrict__ value_w,
               const float* __restrict__ value_b,
               const float* __restrict__ ws,
               float* __restrict__ out){
  __shared__ __align__(16) float S_all[4][NH][DIM];   // 16 KB: per-wave partial S
  __shared__ __align__(16) float Sfin[NH][DIM];       // 4 KB
  __shared__ float sums_all[4][NH];
  __shared__ float invs[NH], wsums[NH];

  const int b   = blockIdx.x;
  const int tid = threadIdx.x;

  const int seg_start = offs[b];
  const int seg_end   = offs[b+1];

  const int wave = tid >> 6, lane = tid & 63;
  const int half = lane >> 5, sl = lane & 31;   // half-wave owns one 256-col row (8 fp32/lane)

  // lane-resident qw fragment: columns sl*8 .. sl*8+7, all 4 heads (fp32, 32 VGPRs)
  float qwr[NH][8];
  #pragma unroll
  for (int h = 0; h < NH; ++h){
    const float4* q4 = (const float4*)(ws + h*DIM + sl*8);
    float4 a = q4[0], c = q4[1];
    qwr[h][0]=a.x; qwr[h][1]=a.y; qwr[h][2]=a.z; qwr[h][3]=a.w;
    qwr[h][4]=c.x; qwr[h][5]=c.y; qwr[h][6]=c.z; qwr[h][7]=c.w;
  }
  float qb[NH];
  #pragma unroll
  for (int h = 0; h < NH; ++h) qb[h] = ws[1024 + h];

  float Sacc[NH][8];
  #pragma unroll
  for (int h = 0; h < NH; ++h)
    #pragma unroll
    for (int c = 0; c < 8; ++c) Sacc[h][c] = 0.f;
  float se[NH] = {0.f, 0.f, 0.f, 0.f};

  const float4* xr4 = (const float4*)x;   // one row = 64 float4 (256 fp32)

  // each (wave,half) processes nodes seg_start + 8k + wave*2 + half (uniform per half-wave)
  for (int n = seg_start + wave*2 + half; n < seg_end; n += 8){
    float4 ra = xr4[(size_t)n * 64 + sl*2];
    float4 rb = xr4[(size_t)n * 64 + sl*2 + 1];
    float xv[8];
    xv[0]=ra.x; xv[1]=ra.y; xv[2]=ra.z; xv[3]=ra.w;
    xv[4]=rb.x; xv[5]=rb.y; xv[6]=rb.z; xv[7]=rb.w;

    float p[NH];
    #pragma unroll
    for (int h = 0; h < NH; ++h){
      float a = 0.f;
      #pragma unroll
      for (int c = 0; c < 8; ++c) a += qwr[h][c] * xv[c];
      p[h] = a;
    }
    // half-wave butterfly (masks <32 stay inside the active half)
    #pragma unroll
    for (int m = 1; m < 32; m <<= 1){
      #pragma unroll
      for (int h = 0; h < NH; ++h) p[h] += __shfl_xor(p[h], m, 64);
    }
    float e[NH];
    #pragma unroll
    for (int h = 0; h < NH; ++h){
      e[h] = __expf((p[h] + qb[h]) * SCL);
      se[h] += e[h];
    }
    #pragma unroll
    for (int h = 0; h < NH; ++h)
      #pragma unroll
      for (int c = 0; c < 8; ++c) Sacc[h][c] += e[h] * xv[c];
  }

  // combine the two halves of each wave (same columns, different nodes)
  #pragma unroll
  for (int h = 0; h < NH; ++h){
    se[h] += __shfl_xor(se[h], 32, 64);
    #pragma unroll
    for (int c = 0; c < 8; ++c) Sacc[h][c] += __shfl_xor(Sacc[h][c], 32, 64);
  }
  if (half == 0){
    #pragma unroll
    for (int h = 0; h < NH; ++h){
      float4 lo = make_float4(Sacc[h][0], Sacc[h][1], Sacc[h][2], Sacc[h][3]);
      float4 hi = make_float4(Sacc[h][4], Sacc[h][5], Sacc[h][6], Sacc[h][7]);
      float4* dst = (float4*)&S_all[wave][h][sl*8];
      dst[0] = lo; dst[1] = hi;
    }
    if (sl == 0){
      #pragma unroll
      for (int h = 0; h < NH; ++h) sums_all[wave][h] = se[h];
    }
  }
  __syncthreads();

  // reduce 4 wave-copies; thread t owns column t
  #pragma unroll
  for (int h = 0; h < NH; ++h)
    Sfin[h][tid] = S_all[0][h][tid] + S_all[1][h][tid] + S_all[2][h][tid] + S_all[3][h][tid];
  if (tid < NH){
    float tot = sums_all[0][tid] + sums_all[1][tid] + sums_all[2][tid] + sums_all[3][tid];
    float inv = 1.f / (tot + EPSV);
    invs[tid]  = inv;
    wsums[tid] = tot * inv;   // sum of normalized weights
  }
  __syncthreads();

  // epilogue: out[b, t] = inv * (value_w[t,:] . Sfin[h,:]) + wsum * value_b[t]
  const int h = tid >> 6;
  const float inv = invs[h], wsm = wsums[h];
  const float4* vrow = (const float4*)(value_w + (size_t)tid * DIM);  // fp32 row, L2-resident
  const float4* sp   = (const float4*)&Sfin[h][0];                    // broadcast reads
  float acc = 0.f;
  #pragma unroll
  for (int q = 0; q < 64; ++q){
    float4 r = vrow[q];
    float4 s = sp[q];
    acc += r.x*s.x + r.y*s.y + r.z*s.z + r.w*s.w;
  }
  out[(size_t)b * DIM + tid] = acc * inv + wsm * value_b[tid];
}

extern "C" void kernel_launch(void* const* d_in, const int* in_sizes, int n_in,
                              void* d_out, int out_size, void* d_ws, size_t ws_size,
                              hipStream_t stream){
  const float* x       = (const float*)d_in[0];
  const int*   batch   = (const int*)d_in[1];
  const float* query   = (const float*)d_in[2];
  const float* key_w   = (const float*)d_in[3];
  const float* key_b   = (const float*)d_in[4];
  const float* value_w = (const float*)d_in[5];
  const float* value_b = (const float*)d_in[6];
  float* ws  = (float*)d_ws;              // [0..1023] qw, [1024..1027] qb
  int*   offs = (int*)(ws + 1088);        // [B+1] segment offsets (16-B aligned)
  float* out = (float*)d_out;

  const int N = in_sizes[1];        // 262144
  const int B = out_size / DIM;     // 4096

  prep_qw<<<4, 256, 0, stream>>>(query, key_w, key_b, ws);
  seg_offsets<<<(N + 255) / 256, 256, 0, stream>>>(batch, offs, N, B);
  attn_pool<<<B, 256, 0, stream>>>(x, offs, value_w, value_b, ws, out);
}

// Round 5
// 466.636 us; speedup vs baseline: 1.0566x; 1.0115x over previous
//
#include <hip/hip_runtime.h>
#include <hip/hip_bf16.h>

// AttentionPooling: N=262144, DIM=256, H=4, HD=64, B=4096 segments (batch sorted).
// Fold query into key_w (qw[4][256], qb[4]); defer value projection to post-pool:
//   pooled[b,o] = inv * (value_w[o,:] . Sraw[b,h,:]) + (sum_e*inv) * value_b[o]
// x (256 MB fp32) read exactly once. One block per segment.
//
// R5 vs R4 (204 us, VALUBusy 17%, ~1 outstanding load/CU -> latency-bound on the
// 5-stage dependent ds_swizzle chain with 8 sequential iterations/stream):
//  - 512-thread blocks: 16 streams/segment -> ~2 sequential iterations each;
//    4 blocks x 8 waves = 32 waves/CU theoretical (LDS 39 KB).
//  - 2-node unroll per stream-iteration: 4 loads in flight, 8 independent
//    shuffle chains back-to-back (amortize crossbar latency ~2x).
//  - epilogue value_w dot split across thread pairs (32 serial L2 loads, not 64).

constexpr int DIM = 256;
constexpr int NH  = 4;
constexpr int HD  = 64;
constexpr float SCL  = 0.125f;   // HD^-0.5
constexpr float EPSV = 1e-8f;

// ---- prep: qw[h][j] = sum_d query[h,d]*key_w[h*64+d, j]; qb[h] = q . key_b ----
__global__ void prep_qw(const float* __restrict__ query,
                        const float* __restrict__ key_w,
                        const float* __restrict__ key_b,
                        float* __restrict__ ws){
  int t = blockIdx.x * 256 + threadIdx.x;   // 0..1023
  int h = t >> 8, j = t & 255;
  float acc = 0.f;
  for (int d = 0; d < HD; ++d)
    acc += query[h*HD+d] * key_w[(size_t)(h*HD+d)*DIM + j];
  ws[t] = acc;
  if (j == 0){
    float bb = 0.f;
    for (int d = 0; d < HD; ++d)
      bb += query[h*HD+d] * key_b[h*HD+d];
    ws[1024 + h] = bb;
  }
}

// ---- segment offsets: offs[b] = first i with batch[i] >= b; offs[B] = N ----
__global__ void seg_offsets(const int* __restrict__ batch32,
                            int* __restrict__ offs, int N, int B){
  int i = blockIdx.x * 256 + threadIdx.x;
  if (i >= N) return;
  const bool is64 = (batch32[N-1] == 0);   // int64 layout: high word of last elem is 0
  int v  = is64 ? batch32[2*i] : batch32[i];
  int vp = (i == 0) ? -1 : (is64 ? batch32[2*(i-1)] : batch32[i-1]);
  for (int b = vp + 1; b <= v; ++b) offs[b] = i;
  if (i == N-1)
    for (int b = v + 1; b <= B; ++b) offs[b] = N;
}

// ---- main: one block (512 thr = 8 waves = 16 streams) per segment ----
__global__ __launch_bounds__(512, 4)
void attn_pool(const float* __restrict__ x,
               const int* __restrict__ offs,
               const float* __restrict__ value_w,
               const float* __restrict__ value_b,
               const float* __restrict__ ws,
               float* __restrict__ out){
  __shared__ __align__(16) float S_all[8][NH][DIM];   // 32 KB per-wave partial S
  __shared__ __align__(16) float Sfin[NH][DIM];       // 4 KB
  __shared__ __align__(16) float ep[2][DIM];          // 2 KB epilogue partials
  __shared__ float sums_all[8][NH];
  __shared__ float invs[NH], wsums[NH];

  const int b   = blockIdx.x;
  const int tid = threadIdx.x;
  const int seg_start = offs[b];
  const int seg_end   = offs[b+1];

  const int wave = tid >> 6, lane = tid & 63;
  const int half = lane >> 5, sl = lane & 31;   // half-wave = one stream
  const int sigma = wave * 2 + half;            // stream id 0..15

  // lane-resident qw fragment: columns sl*8 .. sl*8+7, all 4 heads
  float qwr[NH][8];
  #pragma unroll
  for (int h = 0; h < NH; ++h){
    const float4* q4 = (const float4*)(ws + h*DIM + sl*8);
    float4 a = q4[0], c = q4[1];
    qwr[h][0]=a.x; qwr[h][1]=a.y; qwr[h][2]=a.z; qwr[h][3]=a.w;
    qwr[h][4]=c.x; qwr[h][5]=c.y; qwr[h][6]=c.z; qwr[h][7]=c.w;
  }
  float qb[NH];
  #pragma unroll
  for (int h = 0; h < NH; ++h) qb[h] = ws[1024 + h];

  float Sacc[NH][8];
  #pragma unroll
  for (int h = 0; h < NH; ++h)
    #pragma unroll
    for (int c = 0; c < 8; ++c) Sacc[h][c] = 0.f;
  float se[NH] = {0.f, 0.f, 0.f, 0.f};

  const float4* xr4 = (const float4*)x;   // one row = 64 float4

  // stream sigma handles node pairs (n0, n0+1), n0 = seg_start + 2*sigma + 32k
  for (int n0 = seg_start + sigma*2; n0 < seg_end; n0 += 32){
    const int n1 = n0 + 1;
    const bool has1 = (n1 < seg_end);
    float4 a0 = xr4[(size_t)n0 * 64 + sl*2];
    float4 b0 = xr4[(size_t)n0 * 64 + sl*2 + 1];
    float4 a1 = make_float4(0.f,0.f,0.f,0.f), b1 = a1;
    if (has1){ a1 = xr4[(size_t)n1 * 64 + sl*2]; b1 = xr4[(size_t)n1 * 64 + sl*2 + 1]; }

    float xv0[8] = {a0.x,a0.y,a0.z,a0.w,b0.x,b0.y,b0.z,b0.w};
    float xv1[8] = {a1.x,a1.y,a1.z,a1.w,b1.x,b1.y,b1.z,b1.w};

    float p0[NH], p1[NH];
    #pragma unroll
    for (int h = 0; h < NH; ++h){
      float s0 = 0.f, s1 = 0.f;
      #pragma unroll
      for (int c = 0; c < 8; ++c){ s0 += qwr[h][c]*xv0[c]; s1 += qwr[h][c]*xv1[c]; }
      p0[h] = s0; p1[h] = s1;
    }
    // 8 independent butterfly chains (4 heads x 2 nodes), interleaved per stage
    #pragma unroll
    for (int m = 1; m < 32; m <<= 1){
      #pragma unroll
      for (int h = 0; h < NH; ++h){
        p0[h] += __shfl_xor(p0[h], m, 64);
        p1[h] += __shfl_xor(p1[h], m, 64);
      }
    }
    const float g1 = has1 ? 1.f : 0.f;
    #pragma unroll
    for (int h = 0; h < NH; ++h){
      float e0 = __expf((p0[h] + qb[h]) * SCL);
      float e1 = __expf((p1[h] + qb[h]) * SCL) * g1;  // xv1 already zeroed; gate se too
      se[h] += e0 + e1;
      #pragma unroll
      for (int c = 0; c < 8; ++c)
        Sacc[h][c] += e0*xv0[c] + e1*xv1[c];
    }
  }

  // combine the two streams of each wave (same columns, different nodes)
  #pragma unroll
  for (int h = 0; h < NH; ++h){
    se[h] += __shfl_xor(se[h], 32, 64);
    #pragma unroll
    for (int c = 0; c < 8; ++c) Sacc[h][c] += __shfl_xor(Sacc[h][c], 32, 64);
  }
  if (half == 0){
    #pragma unroll
    for (int h = 0; h < NH; ++h){
      float4 lo = make_float4(Sacc[h][0], Sacc[h][1], Sacc[h][2], Sacc[h][3]);
      float4 hi = make_float4(Sacc[h][4], Sacc[h][5], Sacc[h][6], Sacc[h][7]);
      float4* dst = (float4*)&S_all[wave][h][sl*8];
      dst[0] = lo; dst[1] = hi;
    }
    if (sl == 0){
      #pragma unroll
      for (int h = 0; h < NH; ++h) sums_all[wave][h] = se[h];
    }
  }
  __syncthreads();

  // reduce 8 wave-copies; 1024 values over 512 threads (2 each)
  #pragma unroll
  for (int idx = tid; idx < NH*DIM; idx += 512){
    int h = idx >> 8, c = idx & 255;
    float s = 0.f;
    #pragma unroll
    for (int w = 0; w < 8; ++w) s += S_all[w][h][c];
    Sfin[h][c] = s;
  }
  if (tid < NH){
    float tot = 0.f;
    #pragma unroll
    for (int w = 0; w < 8; ++w) tot += sums_all[w][tid];
    float inv = 1.f / (tot + EPSV);
    invs[tid]  = inv;
    wsums[tid] = tot * inv;
  }
  __syncthreads();

  // epilogue: out[b,t] = inv * (value_w[t,:] . Sfin[h,:]) + wsum * value_b[t]
  // dot split across thread pairs (t, t+256): 32 float4 each
  const int t = tid & 255, part = tid >> 8;
  const int h = t >> 6;
  const float4* vrow = (const float4*)(value_w + (size_t)t * DIM) + part*32;
  const float4* sp   = (const float4*)&Sfin[h][0] + part*32;
  float acc = 0.f;
  #pragma unroll
  for (int q = 0; q < 32; ++q){
    float4 r = vrow[q];
    float4 s = sp[q];
    acc += r.x*s.x + r.y*s.y + r.z*s.z + r.w*s.w;
  }
  ep[part][t] = acc;
  __syncthreads();
  if (part == 0)
    out[(size_t)b * DIM + t] = (ep[0][t] + ep[1][t]) * invs[h] + wsums[h] * value_b[t];
}

extern "C" void kernel_launch(void* const* d_in, const int* in_sizes, int n_in,
                              void* d_out, int out_size, void* d_ws, size_t ws_size,
                              hipStream_t stream){
  const float* x       = (const float*)d_in[0];
  const int*   batch   = (const int*)d_in[1];
  const float* query   = (const float*)d_in[2];
  const float* key_w   = (const float*)d_in[3];
  const float* key_b   = (const float*)d_in[4];
  const float* value_w = (const float*)d_in[5];
  const float* value_b = (const float*)d_in[6];
  float* ws  = (float*)d_ws;              // [0..1023] qw, [1024..1027] qb
  int*   offs = (int*)(ws + 1088);        // [B+1] segment offsets
  float* out = (float*)d_out;

  const int N = in_sizes[1];        // 262144
  const int B = out_size / DIM;     // 4096

  prep_qw<<<4, 256, 0, stream>>>(query, key_w, key_b, ws);
  seg_offsets<<<(N + 255) / 256, 256, 0, stream>>>(batch, offs, N, B);
  attn_pool<<<B, 512, 0, stream>>>(x, offs, value_w, value_b, ws, out);
}